// Round 3
// baseline (93.582 us; speedup 1.0000x reference)
//
#include <hip/hip_runtime.h>

#define N_EVAL 2001
#define NCTRL  64
#define ROWF   (N_EVAL * 3)   // 6003 floats per u-row (== 3 mod 4!)

// degree p = 3; clamped knots: [0,0,0,0, 1/61..60/61, 1,1,1,1] (len 68)
__device__ __forceinline__ float knotv(int i) {
    if (i <= 3) return 0.0f;
    if (i >= NCTRL) return 1.0f;
    return (float)(i - 3) * (1.0f / 61.0f);
}

// Cox-de-Boor degree 3, searchsorted(side='right') span semantics.
// v_rcp_f32 instead of exact divide: ~1 ulp basis error vs 4.3e-2 threshold.
__device__ __forceinline__ void basis_p3(float u, int& span, float4& N) {
    int s = 3 + (int)floorf(u * 61.0f);
    s = max(3, min(63, s));
    while (s < 63 && knotv(s + 1) <= u) ++s;
    while (s > 3 && knotv(s) > u) --s;

    float left[4], right[4], Ns[4];
    Ns[0] = 1.0f;
    #pragma unroll
    for (int j = 1; j <= 3; ++j) {
        left[j]  = u - knotv(s + 1 - j);
        right[j] = knotv(s + j) - u;
        float saved = 0.0f;
        #pragma unroll
        for (int r = 0; r < j; ++r) {
            float temp = Ns[r] * __builtin_amdgcn_rcpf(right[r + 1] + left[j - r]);
            Ns[r] = saved + right[r + 1] * temp;
            saved = left[j - r] * temp;
        }
        Ns[j] = saved;
    }
    span = s;
    N = make_float4(Ns[0], Ns[1], Ns[2], Ns[3]);
}

// One block per u-row. Basis computed inline (no workspace, single kernel).
// Stores: LDS-staged, emitted as 16B-aligned global_store_dwordx4 with a
// per-row shift so odd rows (6003 % 4 == 3) stay on the aligned grid.
__global__ __launch_bounds__(256) void eval_kernel(const float* __restrict__ cp,
                                                   const float* __restrict__ pu,
                                                   const float* __restrict__ pv,
                                                   float* __restrict__ out) {
    __shared__ float4 curve[NCTRL];     // u-contracted row: (x,y,z,pad) per j
    __shared__ float  stage[2][776];    // double buffer: 768 + shift pad; 776*4 % 16 == 0

    const int u = blockIdx.x;
    const int t = threadIdx.x;

    // wave-uniform: every thread computes the same Bu/su (scalar-path cheap)
    int s_u; float4 bu;
    basis_p3(pu[u], s_u, bu);

    // stage 1: 192 threads, one (j,d) each; CP rows = 192 contiguous floats
    if (t < NCTRL * 3) {
        const int base = (s_u - 3) * (NCTRL * 3);
        float c = bu.x * cp[base +       t]
                + bu.y * cp[base + 192 + t]
                + bu.z * cp[base + 384 + t]
                + bu.w * cp[base + 576 + t];
        int j = t / 3, d = t - 3 * j;
        ((float*)curve)[j * 4 + d] = c;
    }
    __syncthreads();

    const size_t rowstart = (size_t)u * ROWF;
    const int shift    = (int)(rowstart & 3);   // row misalignment (0..3)
    const int slotbase = shift ? 4 : 0;         // = head + shift

    for (int k = 0; k < 8; ++k) {
        const int v = k * 256 + t;
        float x = 0.f, y = 0.f, z = 0.f;
        if (v < N_EVAL) {
            int s_v; float4 bv;
            basis_p3(pv[v], s_v, bv);
            const int iv0 = s_v - 3;            // in [0,60]
            float4 c0 = curve[iv0 + 0];
            float4 c1 = curve[iv0 + 1];
            float4 c2 = curve[iv0 + 2];
            float4 c3 = curve[iv0 + 3];
            x = bv.x * c0.x + bv.y * c1.x + bv.z * c2.x + bv.w * c3.x;
            y = bv.x * c0.y + bv.y * c1.y + bv.z * c2.y + bv.w * c3.y;
            z = bv.x * c0.z + bv.y * c1.z + bv.z * c2.z + bv.w * c3.z;
        }
        float* st = stage[k & 1];
        if (v < N_EVAL) {
            // slot s = (local float idx) + shift; stride-3 dword = 2-way bank alias (free)
            st[3 * t + 0 + shift] = x;
            st[3 * t + 1 + shift] = y;
            st[3 * t + 2 + shift] = z;
        }
        __syncthreads();   // single barrier/iter; buffer reuse is 2 iters away -> safe

        const int    g0    = k * 768;                  // row-local float index
        const int    cnt   = (g0 + 768 <= ROWF) ? 768 : (ROWF - g0);   // 768 or 627
        const size_t gabs0 = rowstart + g0;            // (gabs0 & 3) == shift
        const int    head  = (4 - shift) & 3;
        const int    nf    = (cnt - head) >> 2;        // full float4 count (<=192)

        if (t < nf) {
            // LDS b128 read, 16B aligned; global dwordx4 store, 16B aligned
            float4 q = *reinterpret_cast<const float4*>(&st[slotbase + 4 * t]);
            reinterpret_cast<float4*>(out + gabs0 + head)[t] = q;
        }
        // head/tail dwords: wave 3 only (t in 240..246), <=6 lanes active
        if (t >= 240 && t < 240 + head) {
            int h = t - 240;
            out[gabs0 + h] = st[shift + h];
        }
        const int done  = head + 4 * nf;
        const int tailc = cnt - done;                  // 0..3
        if (t >= 244 && t < 244 + tailc) {
            int h = t - 244;
            out[gabs0 + done + h] = st[shift + done + h];
        }
    }
}

extern "C" void kernel_launch(void* const* d_in, const int* in_sizes, int n_in,
                              void* d_out, int out_size, void* d_ws, size_t ws_size,
                              hipStream_t stream) {
    const float* cp = (const float*)d_in[0];   // [64,64,3] f32
    const float* pu = (const float*)d_in[1];   // [2001] f32
    const float* pv = (const float*)d_in[2];   // [2001] f32
    float* out = (float*)d_out;                // [2001,2001,3] f32

    eval_kernel<<<N_EVAL, 256, 0, stream>>>(cp, pu, pv, out);
}

// Round 4
// 82.851 us; speedup vs baseline: 1.1295x; 1.1295x over previous
//
#include <hip/hip_runtime.h>

#define N_EVAL 2001
#define NCTRL  64
#define ROWF   6003   // floats per u-row; 6003 % 4 == 3

// degree p = 3; clamped knots: [0,0,0,0, 1/61..60/61, 1,1,1,1] (len 68)
__device__ __forceinline__ float knotv(int i) {
    if (i <= 3) return 0.0f;
    if (i >= NCTRL) return 1.0f;
    return (float)(i - 3) * (1.0f / 61.0f);
}

// Cox-de-Boor degree 3, searchsorted(side='right') span semantics (exact divides)
__device__ __forceinline__ void basis_p3(float u, int& span, float* Ns) {
    int s = 3 + (int)floorf(u * 61.0f);
    s = max(3, min(63, s));
    while (s < 63 && knotv(s + 1) <= u) ++s;
    while (s > 3 && knotv(s) > u) --s;
    float left[4], right[4];
    Ns[0] = 1.0f;
    #pragma unroll
    for (int j = 1; j <= 3; ++j) {
        left[j]  = u - knotv(s + 1 - j);
        right[j] = knotv(s + j) - u;
        float saved = 0.0f;
        #pragma unroll
        for (int r = 0; r < j; ++r) {
            float temp = Ns[r] / (right[r + 1] + left[j - r]);
            Ns[r] = saved + right[r + 1] * temp;
            saved = left[j - r] * temp;
        }
        Ns[j] = saved;
    }
    span = s;
}

__global__ void basis_kernel(const float* __restrict__ pu, const float* __restrict__ pv,
                             float4* __restrict__ Bu4, int* __restrict__ su,
                             float4* __restrict__ bvp) {
    int gid = blockIdx.x * blockDim.x + threadIdx.x;
    if (gid >= N_EVAL) return;
    int s; float N[4];
    basis_p3(pu[gid], s, N);
    Bu4[gid] = make_float4(N[0], N[1], N[2], N[3]);
    su[gid] = s;
    int s2; float M[4];
    basis_p3(pv[gid], s2, M);
    // packed: b3 reconstructed as 1-b0-b1-b2 (partition of unity, ~1e-7 err)
    bvp[gid] = make_float4(M[0], M[1], M[2], (float)s2);
}

// point eval from packed basis against LDS curve row
__device__ __forceinline__ float3 eval_pt(const float4* __restrict__ curve, float4 q) {
    float b3 = 1.0f - q.x - q.y - q.z;
    int iv0 = (int)q.w - 3;              // span-3 in [0,60]
    float4 c0 = curve[iv0 + 0];
    float4 c1 = curve[iv0 + 1];
    float4 c2 = curve[iv0 + 2];
    float4 c3 = curve[iv0 + 3];
    return make_float3(q.x * c0.x + q.y * c1.x + q.z * c2.x + b3 * c3.x,
                       q.x * c0.y + q.y * c1.y + q.z * c2.y + b3 * c3.y,
                       q.x * c0.z + q.y * c1.z + q.z * c2.z + b3 * c3.z);
}

// One block per u-row; barrier-free main loop; each thread owns aligned
// float4 output slots (one slot = 4 floats spanning 2 adjacent v-points).
__global__ __launch_bounds__(256) void eval_kernel(const float* __restrict__ cp,
                                                   const float4* __restrict__ Bu4,
                                                   const int* __restrict__ su,
                                                   const float4* __restrict__ bvp,
                                                   float* __restrict__ out) {
    __shared__ float4 curve[NCTRL];      // u-contracted row: (x,y,z,pad) per j

    const int u = blockIdx.x;
    const int t = threadIdx.x;
    const int s_u = su[u];               // uniform -> scalar
    const float4 bu = Bu4[u];

    // stage 1: 192 threads, one (j,d) each; CP rows = 192 contiguous floats
    if (t < NCTRL * 3) {
        const int base = (s_u - 3) * (NCTRL * 3);
        float c = bu.x * cp[base +       t]
                + bu.y * cp[base + 192 + t]
                + bu.z * cp[base + 384 + t]
                + bu.w * cp[base + 576 + t];
        int j = t / 3, d = t - 3 * j;
        ((float*)curve)[j * 4 + d] = c;
    }
    __syncthreads();                      // the only barrier

    const size_t S = (size_t)u * ROWF;
    const int shift = (int)(S & 3);
    const int head  = (4 - shift) & 3;    // leading dwords before aligned grid
    const int tail  = 3 - head;           // head + 4*1500 + tail == 6003
    float4* outv = (float4*)(out + S + head);   // 1500 aligned slots, 16B-aligned

    #pragma unroll
    for (int k = 0; k < 6; ++k) {
        const int slot = k * 256 + t;
        if (slot < 1500) {
            const int f  = head + 4 * slot;   // row-local float index
            const int v0 = f / 3;
            const int ph = f - 3 * v0;        // 0,1,2
            float4 q0 = bvp[v0];
            float4 q1 = bvp[v0 + 1];          // v0+1 <= 2000 for all full slots
            float3 P0 = eval_pt(curve, q0);
            float3 P1 = eval_pt(curve, q1);
            float4 r;
            if (ph == 0)      r = make_float4(P0.x, P0.y, P0.z, P1.x);
            else if (ph == 1) r = make_float4(P0.y, P0.z, P1.x, P1.y);
            else              r = make_float4(P0.z, P1.x, P1.y, P1.z);
            outv[slot] = r;                   // contiguous 1KB per wave-instr
        }
    }

    // head: row floats 0..head-1 = components 0..head-1 of point 0
    if (t >= 248 && t < 248 + head) {
        int h = t - 248;
        float3 P = eval_pt(curve, bvp[0]);
        out[S + h] = (h == 0) ? P.x : (h == 1 ? P.y : P.z);
    }
    // tail: last `tail` floats = components 3-tail+h of point 2000
    if (t >= 252 && t < 252 + tail) {
        int h = t - 252;
        float3 P = eval_pt(curve, bvp[2000]);
        int comp = 3 - tail + h;
        out[S + ROWF - tail + h] = (comp == 0) ? P.x : (comp == 1 ? P.y : P.z);
    }
}

extern "C" void kernel_launch(void* const* d_in, const int* in_sizes, int n_in,
                              void* d_out, int out_size, void* d_ws, size_t ws_size,
                              hipStream_t stream) {
    const float* cp = (const float*)d_in[0];   // [64,64,3] f32
    const float* pu = (const float*)d_in[1];   // [2001] f32
    const float* pv = (const float*)d_in[2];   // [2001] f32
    float* out = (float*)d_out;                // [2001,2001,3] f32

    // ws: Bu4 f4[2001] | bvp f4[2001] | su i32[2001]  (~72 KB)
    float4* Bu4 = (float4*)d_ws;
    float4* bvp = Bu4 + N_EVAL;
    int* su = (int*)(bvp + N_EVAL);

    basis_kernel<<<8, 256, 0, stream>>>(pu, pv, Bu4, su, bvp);
    eval_kernel<<<N_EVAL, 256, 0, stream>>>(cp, Bu4, su, bvp, out);
}